// Round 14
// baseline (323.151 us; speedup 1.0000x reference)
//
#include <hip/hip_runtime.h>

// MEGNet-like message passing: N=10000 atoms, E=40000 edges, G=128 graphs
// ATOM=32, EDGE=32, STATE=16, D=48, STEPS=2
#define N_ATOMS 10000
#define N_EDGES 40000
#define N_GRAPH 128

typedef unsigned short ushort_t;
typedef __attribute__((ext_vector_type(8))) short bf16x8;
typedef __attribute__((ext_vector_type(4))) float f32x4;

__device__ __forceinline__ ushort_t f2bf(float f) {
    unsigned int u = __float_as_uint(f);
    unsigned int r = (u + 0x7fffu + ((u >> 16) & 1u)) >> 16;   // RNE
    return (ushort_t)r;
}
__device__ __forceinline__ float bf2f(ushort_t u) { return __uint_as_float(((unsigned int)u) << 16); }
__device__ __forceinline__ float bflo(unsigned int u) { return __uint_as_float(u << 16); }
__device__ __forceinline__ float bfhi(unsigned int u) { return __uint_as_float(u & 0xffff0000u); }

// ================= weight transpose/pack (once per launch) =================
__global__ void trans_k(const float* __restrict__ We, const float* __restrict__ Ue,
                        const float* __restrict__ Wn, const float* __restrict__ Un,
                        const float* __restrict__ kernelw,
                        float* __restrict__ wta, float* __restrict__ wts,
                        float* __restrict__ wtee, float* __restrict__ wtn,
                        float* __restrict__ wtun, ushort_t* __restrict__ kb)
{
    int idx = blockIdx.x * 256 + threadIdx.x;   // 372*256 = 95232 exact
    if (idx < 6144) {
        int c = idx / 32, k = idx % 32;
        int col = c % 96;
        int srck = (c < 96) ? k : 32 + k;
        wta[idx] = We[srck * 96 + col];
    } else if (idx < 7680) {
        int j = idx - 6144; int c = j / 16, k = j % 16;
        wts[j] = We[(64 + k) * 96 + c];
    } else if (idx < 13824) {
        int j = idx - 7680; int c = j / 32, k = j % 32;
        wtee[j] = (c < 96) ? We[(80 + k) * 96 + c] : Ue[k * 96 + (c - 96)];
    } else if (idx < 18432) {
        int j = idx - 13824; int c = j / 48, k = j % 48;
        wtn[j] = Wn[k * 96 + c];
    } else if (idx < 21504) {
        int j = idx - 18432; int c = j / 32, k = j % 32;
        wtun[j] = Un[k * 96 + c];
    } else {
        int j = idx - 21504;                    // 0 .. 73727
        kb[j] = f2bf(kernelw[j]);
    }
}

// ================= rowptr over sorted src (once per launch) =================
// rowptr[n] = first edge index with src >= n ; edges of node n: [rowptr[n], rowptr[n+1])
__global__ void rowptr_k(const int* __restrict__ pair, int* __restrict__ rowptr)
{
    int n = blockIdx.x * 256 + threadIdx.x;     // 41*256 = 10496 >= 10001
    if (n > N_ATOMS) return;
    int lo = 0, hi = N_EDGES;
    while (lo < hi) {
        int mid = (lo + hi) >> 1;
        if (pair[2 * mid] < n) lo = mid + 1; else hi = mid;
    }
    rowptr[n] = lo;
}

// ================= PA[n][c] = a[n] . WTa[c]  (c in [0,192)) =================
__global__ __launch_bounds__(192) void pa_k(const float* __restrict__ a,
                                            const float* __restrict__ wta,
                                            float* __restrict__ PA)
{
    __shared__ float as_[16][32];
    int t = threadIdx.x;
    int n0 = blockIdx.x * 16;
    if (t < 128) reinterpret_cast<float4*>(&as_[0][0])[t] =
        reinterpret_cast<const float4*>(a + (size_t)n0 * 32)[t];
    __syncthreads();

    float w[32];
    const float4* wp4 = reinterpret_cast<const float4*>(wta + t * 32);
    #pragma unroll
    for (int q = 0; q < 8; ++q) {
        float4 v = wp4[q];
        w[4*q] = v.x; w[4*q+1] = v.y; w[4*q+2] = v.z; w[4*q+3] = v.w;
    }
    #pragma unroll
    for (int i = 0; i < 16; ++i) {
        float sres = 0.f;
        #pragma unroll
        for (int k = 0; k < 32; ++k) sres += as_[i][k] * w[k];
        PA[(size_t)(n0 + i) * 192 + t] = sres;
    }
}

// ================= PS[g][c] = s[g] . WTs[c] + be_in[c]  (c in [0,96)) =================
__global__ __launch_bounds__(96) void ps_k(const float* __restrict__ s,
                                           const float* __restrict__ wts,
                                           const float* __restrict__ be_in,
                                           float* __restrict__ PS)
{
    __shared__ float ss[16][16];
    int t = threadIdx.x;
    int g0 = blockIdx.x * 16;
    if (t < 64) reinterpret_cast<float4*>(&ss[0][0])[t] =
        reinterpret_cast<const float4*>(s + (size_t)g0 * 16)[t];
    __syncthreads();

    float w[16];
    const float4* wp4 = reinterpret_cast<const float4*>(wts + t * 16);
    #pragma unroll
    for (int q = 0; q < 4; ++q) {
        float4 v = wp4[q];
        w[4*q] = v.x; w[4*q+1] = v.y; w[4*q+2] = v.z; w[4*q+3] = v.w;
    }
    float b = be_in[t];
    #pragma unroll
    for (int i = 0; i < 16; ++i) {
        float sres = b;
        #pragma unroll
        for (int k = 0; k < 16; ++k) sres += ss[i][k] * w[k];
        PS[(size_t)(g0 + i) * 96 + t] = sres;
    }
}

// ================= fused edge GRU: per-edge GEMM (S in LDS) + gates =================
// 16 edges/block, 192 threads. S[e][c]: c<96 = e@We_e ; c>=96 = e@Ue + be_rec.
// esum: per-block LDS pre-reduction (bgi sorted -> ~1 graph/block), then <=few atomics.
__global__ __launch_bounds__(192) void edge_fused_k(const float* __restrict__ e_in,
                                                    const float* __restrict__ wtee,
                                                    const float* __restrict__ be_rec,
                                                    const float* __restrict__ PA,
                                                    const float* __restrict__ PS,
                                                    const int* __restrict__ pair,
                                                    const int* __restrict__ bgi,
                                                    float* __restrict__ e_out,
                                                    float* __restrict__ esum)
{
    __shared__ float es[16][32];
    __shared__ float S[16][192];
    __shared__ int garr[16];
    int t = threadIdx.x;
    int e0b = blockIdx.x * 16;

    if (t < 128) reinterpret_cast<float4*>(&es[0][0])[t] =
        reinterpret_cast<const float4*>(e_in + (size_t)e0b * 32)[t];
    if (t >= 128 && t < 144) garr[t - 128] = bgi[e0b + (t - 128)];
    __syncthreads();

    float w[32];
    const float4* wp4 = reinterpret_cast<const float4*>(wtee + t * 32);
    #pragma unroll
    for (int q = 0; q < 8; ++q) {
        float4 v = wp4[q];
        w[4*q] = v.x; w[4*q+1] = v.y; w[4*q+2] = v.z; w[4*q+3] = v.w;
    }
    float b = (t >= 96) ? be_rec[t - 96] : 0.f;
    #pragma unroll 4
    for (int i = 0; i < 16; ++i) {
        float sres = b;
        #pragma unroll
        for (int k = 0; k < 32; ++k) sres += es[i][k] * w[k];
        S[i][t] = sres;
    }
    __syncthreads();

    for (int idx = t; idx < 512; idx += 192) {
        int le = idx >> 5, cc = idx & 31;
        int eid = e0b + le;
        int src = pair[2 * eid], dst = pair[2 * eid + 1];
        const float* pas = PA + (size_t)src * 192;
        const float* pad = PA + (size_t)dst * 192 + 96;
        const float* ps  = PS + (size_t)garr[le] * 96;
        float xz = pas[cc]      + pad[cc]      + ps[cc]      + S[le][cc];
        float xr = pas[32 + cc] + pad[32 + cc] + ps[32 + cc] + S[le][32 + cc];
        float xh = pas[64 + cc] + pad[64 + cc] + ps[64 + cc] + S[le][64 + cc];
        float hz = S[le][96 + cc], hr = S[le][128 + cc], hh = S[le][160 + cc];
        float h  = es[le][cc];
        float z  = 1.f / (1.f + expf(-(xz + hz)));
        float r  = 1.f / (1.f + expf(-(xr + hr)));
        float hc = tanhf(xh + r * hh);
        float val = z * h + (1.f - z) * hc;
        e_out[(size_t)eid * 32 + cc] = val;
        es[le][cc] = val;                       // stash for block-level esum reduction
    }
    __syncthreads();

    // per-block segment reduction over sorted bgi, then one atomic per (segment, channel)
    if (t < 32) {
        int cc = t;
        int gprev = garr[0];
        float run = 0.f;
        #pragma unroll 4
        for (int le = 0; le < 16; ++le) {
            int gcur = garr[le];                // wave-uniform
            if (gcur != gprev) {
                atomicAdd(&esum[gprev * 32 + cc], run);
                run = 0.f; gprev = gcur;
            }
            run += es[le][cc];
        }
        atomicAdd(&esum[gprev * 32 + cc], run);
    }
}

// ================= Y via MFMA: Yp[n][i*32+kk] = dot(kernel[kk, i*48..+48], amc[n]) =====
__global__ __launch_bounds__(256) void y_mfma_k(const ushort_t* __restrict__ kb,
                                                const float* __restrict__ bias,
                                                const float* __restrict__ a,
                                                const float* __restrict__ s,
                                                const int* __restrict__ agi,
                                                ushort_t* __restrict__ Yb,
                                                float* __restrict__ Bn)
{
    __shared__ ushort_t amcs[32][64];
    int t = threadIdx.x;
    int n0 = blockIdx.x * 32;

    for (int idx = t; idx < 32 * 64; idx += 256) {
        int row = idx >> 6, j = idx & 63;
        int n = n0 + row;
        float v = 0.f;
        if (n < N_ATOMS) {
            if (j < 32)      v = a[(size_t)n * 32 + j];
            else if (j < 48) v = s[agi[n] * 16 + (j - 32)];
        }
        amcs[row][j] = f2bf(v);
    }
    __syncthreads();

    int lane = t & 63;
    int wv = t >> 6;
    int cl = lane & 15;
    int g  = lane >> 4;

    bf16x8 zero8 = {0, 0, 0, 0, 0, 0, 0, 0};

    bf16x8 A[2][2];
    #pragma unroll
    for (int mt = 0; mt < 2; ++mt) {
        #pragma unroll
        for (int kh = 0; kh < 2; ++kh) {
            A[mt][kh] = *reinterpret_cast<const bf16x8*>(&amcs[mt * 16 + cl][kh * 32 + g * 8]);
        }
    }

    for (int nt = wv; nt < 96; nt += 4) {
        int c = nt * 16 + cl;
        int kk = c & 31, ii = c >> 5;
        const ushort_t* kbase = kb + (size_t)kk * 2304 + ii * 48;
        bf16x8 B0 = *reinterpret_cast<const bf16x8*>(kbase + g * 8);
        bf16x8 B1 = (g < 2) ? *reinterpret_cast<const bf16x8*>(kbase + 32 + g * 8) : zero8;
        #pragma unroll
        for (int mt = 0; mt < 2; ++mt) {
            f32x4 acc = {0.f, 0.f, 0.f, 0.f};
            acc = __builtin_amdgcn_mfma_f32_16x16x32_bf16(A[mt][0], B0, acc, 0, 0, 0);
            acc = __builtin_amdgcn_mfma_f32_16x16x32_bf16(A[mt][1], B1, acc, 0, 0, 0);
            #pragma unroll
            for (int r = 0; r < 4; ++r) {
                int n = n0 + mt * 16 + g * 4 + r;
                if (n < N_ATOMS) Yb[(size_t)n * 1536 + c] = f2bf(acc[r]);
            }
        }
    }

    // Bn[n][i] = dot(bias[i*48..+48], amc[n])  (bf16 amc, f32 bias/accum)
    for (int idx = t; idx < 32 * 48; idx += 256) {
        int row = idx / 48, i = idx % 48;
        int n = n0 + row;
        if (n >= N_ATOMS) continue;
        const float* bb = bias + i * 48;
        float accv = 0.f;
        #pragma unroll
        for (int j = 0; j < 48; ++j) accv += bb[j] * bf2f(amcs[row][j]);
        Bn[(size_t)n * 48 + i] = accv;
    }
}

// ================= node-centric message aggregation (CSR over sorted src, NO atomics) =====
// 4 waves/block, wave = one node; lanes 0..47: agg[n][i] = sum_e t[e][i], plain store.
__global__ __launch_bounds__(256) void node_agg_k(const float* __restrict__ e_new,
                                                  const int* __restrict__ pair,
                                                  const ushort_t* __restrict__ Yb,
                                                  const float* __restrict__ Bn,
                                                  const int* __restrict__ rowptr,
                                                  float* __restrict__ agg)
{
    int t = threadIdx.x;
    int lane = t & 63;
    int n = blockIdx.x * 4 + (t >> 6);
    if (n >= N_ATOMS || lane >= 48) return;

    int e0 = rowptr[n], e1 = rowptr[n + 1];
    float acc = 0.f;
    for (int eid = e0; eid < e1; ++eid) {
        int dst = pair[2 * eid + 1];
        float ev[32];
        const float4* ep = reinterpret_cast<const float4*>(e_new + (size_t)eid * 32);
        #pragma unroll
        for (int q = 0; q < 8; ++q) {
            float4 v = ep[q];
            ev[4*q] = v.x; ev[4*q+1] = v.y; ev[4*q+2] = v.z; ev[4*q+3] = v.w;
        }
        const uint4* yp = reinterpret_cast<const uint4*>(Yb + (size_t)dst * 1536 + lane * 32);
        float sres = Bn[dst * 48 + lane];
        #pragma unroll
        for (int q = 0; q < 4; ++q) {
            uint4 v = yp[q];
            int k = q * 8;
            sres += bflo(v.x) * ev[k]     + bfhi(v.x) * ev[k + 1]
                  + bflo(v.y) * ev[k + 2] + bfhi(v.y) * ev[k + 3]
                  + bflo(v.z) * ev[k + 4] + bfhi(v.z) * ev[k + 5]
                  + bflo(v.w) * ev[k + 6] + bfhi(v.w) * ev[k + 7];
        }
        acc += sres;
    }
    agg[(size_t)n * 48 + lane] = acc;           // deg-0 nodes write 0 (no memset needed)
}

// ================= fused node GRU: GEMM (S in LDS) + gates =================
// 16 nodes/block, 192 threads. asum via per-block sorted-agi reduction.
__global__ __launch_bounds__(192) void node_fused_k(const float* __restrict__ agg,
                                                    const float* __restrict__ a_in,
                                                    const float* __restrict__ wtn,
                                                    const float* __restrict__ wtun,
                                                    const float* __restrict__ bn_in,
                                                    const float* __restrict__ bn_rec,
                                                    const int* __restrict__ agi,
                                                    float* __restrict__ a_out,
                                                    float* __restrict__ asum)
{
    __shared__ float xs[16][48];
    __shared__ float hs[16][32];
    __shared__ float S[16][192];
    __shared__ int garr[16];
    int t = threadIdx.x;
    int n0 = blockIdx.x * 16;

    reinterpret_cast<float4*>(&xs[0][0])[t] =
        reinterpret_cast<const float4*>(agg + (size_t)n0 * 48)[t];       // 192 float4
    if (t < 128) reinterpret_cast<float4*>(&hs[0][0])[t] =
        reinterpret_cast<const float4*>(a_in + (size_t)n0 * 32)[t];
    if (t >= 128 && t < 144) garr[t - 128] = agi[n0 + (t - 128)];
    __syncthreads();

    if (t < 96) {
        float w[48];
        const float4* wp4 = reinterpret_cast<const float4*>(wtn + t * 48);
        #pragma unroll
        for (int q = 0; q < 12; ++q) {
            float4 v = wp4[q];
            w[4*q] = v.x; w[4*q+1] = v.y; w[4*q+2] = v.z; w[4*q+3] = v.w;
        }
        float b = bn_in[t];
        #pragma unroll 4
        for (int i = 0; i < 16; ++i) {
            float sres = b;
            #pragma unroll
            for (int k = 0; k < 48; ++k) sres += xs[i][k] * w[k];
            S[i][t] = sres;
        }
    } else {
        float w[32];
        const float4* wp4 = reinterpret_cast<const float4*>(wtun + (t - 96) * 32);
        #pragma unroll
        for (int q = 0; q < 8; ++q) {
            float4 v = wp4[q];
            w[4*q] = v.x; w[4*q+1] = v.y; w[4*q+2] = v.z; w[4*q+3] = v.w;
        }
        float b = bn_rec[t - 96];
        #pragma unroll 4
        for (int i = 0; i < 16; ++i) {
            float sres = b;
            #pragma unroll
            for (int k = 0; k < 32; ++k) sres += hs[i][k] * w[k];
            S[i][t] = sres;
        }
    }
    __syncthreads();

    for (int idx = t; idx < 512; idx += 192) {
        int le = idx >> 5, cc = idx & 31;
        int n = n0 + le;
        float z  = 1.f / (1.f + expf(-(S[le][cc] + S[le][96 + cc])));
        float r  = 1.f / (1.f + expf(-(S[le][32 + cc] + S[le][128 + cc])));
        float hc = tanhf(S[le][64 + cc] + r * S[le][160 + cc]);
        float h  = hs[le][cc];
        float val = z * h + (1.f - z) * hc;
        a_out[(size_t)n * 32 + cc] = val;
        hs[le][cc] = val;                       // stash for block-level asum reduction
    }
    __syncthreads();

    if (t < 32) {
        int cc = t;
        int gprev = garr[0];
        float run = 0.f;
        #pragma unroll 4
        for (int le = 0; le < 16; ++le) {
            int gcur = garr[le];                // wave-uniform
            if (gcur != gprev) {
                atomicAdd(&asum[gprev * 32 + cc], run);
                run = 0.f; gprev = gcur;
            }
            run += hs[le][cc];
        }
        atomicAdd(&asum[gprev * 32 + cc], run);
    }
}

// ================= state GRU =================
__global__ void state_gru_k(const float* __restrict__ asum, const float* __restrict__ esum,
                            const float* __restrict__ s_in,
                            const float* __restrict__ Ws, const float* __restrict__ Us,
                            const float* __restrict__ bs_in, const float* __restrict__ bs_rec,
                            float* __restrict__ s_out)
{
    __shared__ float xs[80];
    __shared__ float hsv[16];
    __shared__ float S[48];
    __shared__ float Uh[16];
    int g = blockIdx.x;
    int t = threadIdx.x;
    if (t < 80) {
        float v;
        if (t < 32)      v = asum[g * 32 + t];
        else if (t < 64) v = esum[g * 32 + (t - 32)];
        else             v = s_in[g * 16 + (t - 64)];
        xs[t] = v;
        if (t >= 64) hsv[t - 64] = v;
    }
    __syncthreads();
    if (t < 48) {
        float gacc = bs_in[t];
        #pragma unroll
        for (int k = 0; k < 80; ++k) gacc += xs[k] * Ws[k * 48 + t];
        float u = bs_rec[t];
        #pragma unroll
        for (int k = 0; k < 16; ++k) u += hsv[k] * Us[k * 48 + t];
        if (t < 32) { S[t] = gacc + u; }
        else        { S[t] = gacc; Uh[t - 32] = u; }
    }
    __syncthreads();
    if (t < 16) {
        float z  = 1.f / (1.f + expf(-S[t]));
        float r  = 1.f / (1.f + expf(-S[16 + t]));
        float hc = tanhf(S[32 + t] + r * Uh[t]);
        s_out[g * 16 + t] = z * hsv[t] + (1.f - z) * hc;
    }
}

extern "C" void kernel_launch(void* const* d_in, const int* in_sizes, int n_in,
                              void* d_out, int out_size, void* d_ws, size_t ws_size,
                              hipStream_t stream)
{
    const float* a0      = (const float*)d_in[0];
    const float* e0      = (const float*)d_in[1];
    const float* s0      = (const float*)d_in[2];
    const int*   pair    = (const int*)d_in[3];
    const int*   agi     = (const int*)d_in[4];
    const int*   bgi     = (const int*)d_in[5];
    const float* kernelw = (const float*)d_in[6];
    const float* bias    = (const float*)d_in[7];
    const float* We      = (const float*)d_in[8];
    const float* Ue      = (const float*)d_in[9];
    const float* be_in   = (const float*)d_in[10];
    const float* be_rec  = (const float*)d_in[11];
    const float* Wn      = (const float*)d_in[12];
    const float* Un      = (const float*)d_in[13];
    const float* bn_in   = (const float*)d_in[14];
    const float* bn_rec  = (const float*)d_in[15];
    const float* Ws      = (const float*)d_in[16];
    const float* Us      = (const float*)d_in[17];
    const float* bs_in   = (const float*)d_in[18];
    const float* bs_rec  = (const float*)d_in[19];

    float* out_a = (float*)d_out;                    // N*32
    float* out_e = out_a + N_ATOMS * 32;             // E*32
    float* out_s = out_e + (size_t)N_EDGES * 32;     // G*16

    char* wp = (char*)d_ws;
    auto alloc = [&](size_t nf) { float* p = (float*)wp; wp += nf * sizeof(float); return p; };
    float* aW   = alloc((size_t)N_ATOMS * 32);
    float* eW   = alloc((size_t)N_EDGES * 32);
    float* sW   = alloc((size_t)N_GRAPH * 16);
    ushort_t* Yb = (ushort_t*)alloc((size_t)N_ATOMS * 1536 / 2);  // bf16, 30.7 MB
    float* Bn   = alloc((size_t)N_ATOMS * 48);
    float* agg  = alloc((size_t)N_ATOMS * 48);
    float* asum = alloc((size_t)N_GRAPH * 32);       // asum..esum contiguous memset
    float* esum = alloc((size_t)N_GRAPH * 32);
    float* PA   = alloc((size_t)N_ATOMS * 192);
    float* PS   = alloc((size_t)N_GRAPH * 96);
    float* wta  = alloc(6144);
    float* wts  = alloc(1536);
    float* wtee = alloc(6144);
    float* wtn  = alloc(4608);
    float* wtun = alloc(3072);
    ushort_t* kb = (ushort_t*)alloc(36864);          // 73728 bf16 = kernel(32x2304)
    int* rowptr = (int*)alloc(N_ATOMS + 1);
    size_t zero_bytes = (size_t)2 * N_GRAPH * 32 * sizeof(float);

    trans_k<<<372, 256, 0, stream>>>(We, Ue, Wn, Un, kernelw,
                                     wta, wts, wtee, wtn, wtun, kb);
    rowptr_k<<<41, 256, 0, stream>>>(pair, rowptr);

    const float* a_in = a0;
    const float* e_in = e0;
    const float* s_in = s0;

    for (int step = 0; step < 2; ++step) {
        float* a_o = (step == 0) ? aW : out_a;
        float* e_o = (step == 0) ? eW : out_e;
        float* s_o = (step == 0) ? sW : out_s;

        hipMemsetAsync(asum, 0, zero_bytes, stream);
        pa_k<<<N_ATOMS / 16, 192, 0, stream>>>(a_in, wta, PA);
        ps_k<<<N_GRAPH / 16, 96, 0, stream>>>(s_in, wts, be_in, PS);
        edge_fused_k<<<N_EDGES / 16, 192, 0, stream>>>(e_in, wtee, be_rec, PA, PS,
                                                       pair, bgi, e_o, esum);
        y_mfma_k<<<(N_ATOMS + 31) / 32, 256, 0, stream>>>(kb, bias, a_in, s_in, agi, Yb, Bn);
        node_agg_k<<<(N_ATOMS + 3) / 4, 256, 0, stream>>>(e_o, pair, Yb, Bn, rowptr, agg);
        node_fused_k<<<N_ATOMS / 16, 192, 0, stream>>>(agg, a_in, wtn, wtun,
                                                       bn_in, bn_rec, agi, a_o, asum);
        state_gru_k<<<N_GRAPH, 128, 0, stream>>>(asum, esum, s_in, Ws, Us, bs_in, bs_rec, s_o);

        a_in = a_o; e_in = e_o; s_in = s_o;
    }
}

// Round 16
// 316.813 us; speedup vs baseline: 1.0200x; 1.0200x over previous
//
#include <hip/hip_runtime.h>

// MEGNet-like message passing: N=10000 atoms, E=40000 edges, G=128 graphs
// ATOM=32, EDGE=32, STATE=16, D=48, STEPS=2
#define N_ATOMS 10000
#define N_EDGES 40000
#define N_GRAPH 128

typedef unsigned short ushort_t;
typedef __attribute__((ext_vector_type(8))) short bf16x8;
typedef __attribute__((ext_vector_type(4))) float f32x4;

__device__ __forceinline__ ushort_t f2bf(float f) {
    unsigned int u = __float_as_uint(f);
    unsigned int r = (u + 0x7fffu + ((u >> 16) & 1u)) >> 16;   // RNE
    return (ushort_t)r;
}
__device__ __forceinline__ float bf2f(ushort_t u) { return __uint_as_float(((unsigned int)u) << 16); }
__device__ __forceinline__ float bflo(unsigned int u) { return __uint_as_float(u << 16); }
__device__ __forceinline__ float bfhi(unsigned int u) { return __uint_as_float(u & 0xffff0000u); }

// ================= weight transpose/pack (once per launch) =================
__global__ void trans_k(const float* __restrict__ We, const float* __restrict__ Ue,
                        const float* __restrict__ Wn, const float* __restrict__ Un,
                        const float* __restrict__ kernelw,
                        float* __restrict__ wta, float* __restrict__ wts,
                        float* __restrict__ wtee, float* __restrict__ wtn,
                        float* __restrict__ wtun, ushort_t* __restrict__ kb)
{
    int idx = blockIdx.x * 256 + threadIdx.x;   // 372*256 = 95232 exact
    if (idx < 6144) {
        int c = idx / 32, k = idx % 32;
        int col = c % 96;
        int srck = (c < 96) ? k : 32 + k;
        wta[idx] = We[srck * 96 + col];
    } else if (idx < 7680) {
        int j = idx - 6144; int c = j / 16, k = j % 16;
        wts[j] = We[(64 + k) * 96 + c];
    } else if (idx < 13824) {
        int j = idx - 7680; int c = j / 32, k = j % 32;
        wtee[j] = (c < 96) ? We[(80 + k) * 96 + c] : Ue[k * 96 + (c - 96)];
    } else if (idx < 18432) {
        int j = idx - 13824; int c = j / 48, k = j % 48;
        wtn[j] = Wn[k * 96 + c];
    } else if (idx < 21504) {
        int j = idx - 18432; int c = j / 32, k = j % 32;
        wtun[j] = Un[k * 96 + c];
    } else {
        int j = idx - 21504;                    // 0 .. 73727
        kb[j] = f2bf(kernelw[j]);
    }
}

// ================= PA[n][c] = a[n] . WTa[c]  (c in [0,192)) =================
__global__ __launch_bounds__(192) void pa_k(const float* __restrict__ a,
                                            const float* __restrict__ wta,
                                            float* __restrict__ PA)
{
    __shared__ float as_[16][32];
    int t = threadIdx.x;
    int n0 = blockIdx.x * 16;
    if (t < 128) reinterpret_cast<float4*>(&as_[0][0])[t] =
        reinterpret_cast<const float4*>(a + (size_t)n0 * 32)[t];
    __syncthreads();

    float w[32];
    const float4* wp4 = reinterpret_cast<const float4*>(wta + t * 32);
    #pragma unroll
    for (int q = 0; q < 8; ++q) {
        float4 v = wp4[q];
        w[4*q] = v.x; w[4*q+1] = v.y; w[4*q+2] = v.z; w[4*q+3] = v.w;
    }
    #pragma unroll
    for (int i = 0; i < 16; ++i) {
        float sres = 0.f;
        #pragma unroll
        for (int k = 0; k < 32; ++k) sres += as_[i][k] * w[k];
        PA[(size_t)(n0 + i) * 192 + t] = sres;
    }
}

// ================= PS[g][c] = s[g] . WTs[c] + be_in[c]  (c in [0,96)) =================
__global__ __launch_bounds__(96) void ps_k(const float* __restrict__ s,
                                           const float* __restrict__ wts,
                                           const float* __restrict__ be_in,
                                           float* __restrict__ PS)
{
    __shared__ float ss[16][16];
    int t = threadIdx.x;
    int g0 = blockIdx.x * 16;
    if (t < 64) reinterpret_cast<float4*>(&ss[0][0])[t] =
        reinterpret_cast<const float4*>(s + (size_t)g0 * 16)[t];
    __syncthreads();

    float w[16];
    const float4* wp4 = reinterpret_cast<const float4*>(wts + t * 16);
    #pragma unroll
    for (int q = 0; q < 4; ++q) {
        float4 v = wp4[q];
        w[4*q] = v.x; w[4*q+1] = v.y; w[4*q+2] = v.z; w[4*q+3] = v.w;
    }
    float b = be_in[t];
    #pragma unroll
    for (int i = 0; i < 16; ++i) {
        float sres = b;
        #pragma unroll
        for (int k = 0; k < 16; ++k) sres += ss[i][k] * w[k];
        PS[(size_t)(g0 + i) * 96 + t] = sres;
    }
}

// ================= fused edge GRU: per-edge GEMM (S in LDS) + gates =================
// 16 edges/block, 192 threads. esum via per-block sorted-bgi reduction.
__global__ __launch_bounds__(192) void edge_fused_k(const float* __restrict__ e_in,
                                                    const float* __restrict__ wtee,
                                                    const float* __restrict__ be_rec,
                                                    const float* __restrict__ PA,
                                                    const float* __restrict__ PS,
                                                    const int* __restrict__ pair,
                                                    const int* __restrict__ bgi,
                                                    float* __restrict__ e_out,
                                                    float* __restrict__ esum)
{
    __shared__ float es[16][32];
    __shared__ float S[16][192];
    __shared__ int garr[16];
    int t = threadIdx.x;
    int e0b = blockIdx.x * 16;

    if (t < 128) reinterpret_cast<float4*>(&es[0][0])[t] =
        reinterpret_cast<const float4*>(e_in + (size_t)e0b * 32)[t];
    if (t >= 128 && t < 144) garr[t - 128] = bgi[e0b + (t - 128)];
    __syncthreads();

    float w[32];
    const float4* wp4 = reinterpret_cast<const float4*>(wtee + t * 32);
    #pragma unroll
    for (int q = 0; q < 8; ++q) {
        float4 v = wp4[q];
        w[4*q] = v.x; w[4*q+1] = v.y; w[4*q+2] = v.z; w[4*q+3] = v.w;
    }
    float b = (t >= 96) ? be_rec[t - 96] : 0.f;
    #pragma unroll 4
    for (int i = 0; i < 16; ++i) {
        float sres = b;
        #pragma unroll
        for (int k = 0; k < 32; ++k) sres += es[i][k] * w[k];
        S[i][t] = sres;
    }
    __syncthreads();

    for (int idx = t; idx < 512; idx += 192) {
        int le = idx >> 5, cc = idx & 31;
        int eid = e0b + le;
        int src = pair[2 * eid], dst = pair[2 * eid + 1];
        const float* pas = PA + (size_t)src * 192;
        const float* pad = PA + (size_t)dst * 192 + 96;
        const float* ps  = PS + (size_t)garr[le] * 96;
        float xz = pas[cc]      + pad[cc]      + ps[cc]      + S[le][cc];
        float xr = pas[32 + cc] + pad[32 + cc] + ps[32 + cc] + S[le][32 + cc];
        float xh = pas[64 + cc] + pad[64 + cc] + ps[64 + cc] + S[le][64 + cc];
        float hz = S[le][96 + cc], hr = S[le][128 + cc], hh = S[le][160 + cc];
        float h  = es[le][cc];
        float z  = 1.f / (1.f + expf(-(xz + hz)));
        float r  = 1.f / (1.f + expf(-(xr + hr)));
        float hc = tanhf(xh + r * hh);
        float val = z * h + (1.f - z) * hc;
        e_out[(size_t)eid * 32 + cc] = val;
        es[le][cc] = val;                       // stash for block-level esum reduction
    }
    __syncthreads();

    if (t < 32) {
        int cc = t;
        int gprev = garr[0];
        float run = 0.f;
        #pragma unroll 4
        for (int le = 0; le < 16; ++le) {
            int gcur = garr[le];                // wave-uniform
            if (gcur != gprev) {
                atomicAdd(&esum[gprev * 32 + cc], run);
                run = 0.f; gprev = gcur;
            }
            run += es[le][cc];
        }
        atomicAdd(&esum[gprev * 32 + cc], run);
    }
}

// ================= Y via MFMA + LDS-staged coalesced store =================
// 32 nodes/block, 256 thr = 4 waves. 4 quadrants of 384 channels; per quadrant each
// wave computes 6 N-tiles into sY, then all threads store 16B-coalesced to Yb.
__global__ __launch_bounds__(256) void y_mfma_k(const ushort_t* __restrict__ kb,
                                                const float* __restrict__ bias,
                                                const float* __restrict__ a,
                                                const float* __restrict__ s,
                                                const int* __restrict__ agi,
                                                ushort_t* __restrict__ Yb,
                                                float* __restrict__ Bn)
{
    __shared__ ushort_t amcs[32][64];
    __shared__ ushort_t sY[32][392];            // 384 used + 8 pad (bank spread)
    int t = threadIdx.x;
    int n0 = blockIdx.x * 32;

    for (int idx = t; idx < 32 * 64; idx += 256) {
        int row = idx >> 6, j = idx & 63;
        int n = n0 + row;
        float v = 0.f;
        if (n < N_ATOMS) {
            if (j < 32)      v = a[(size_t)n * 32 + j];
            else if (j < 48) v = s[agi[n] * 16 + (j - 32)];
        }
        amcs[row][j] = f2bf(v);
    }
    __syncthreads();

    int lane = t & 63;
    int wv = t >> 6;
    int cl = lane & 15;
    int g  = lane >> 4;

    bf16x8 zero8 = {0, 0, 0, 0, 0, 0, 0, 0};

    bf16x8 A[2][2];
    #pragma unroll
    for (int mt = 0; mt < 2; ++mt) {
        #pragma unroll
        for (int kh = 0; kh < 2; ++kh) {
            A[mt][kh] = *reinterpret_cast<const bf16x8*>(&amcs[mt * 16 + cl][kh * 32 + g * 8]);
        }
    }

    for (int ch = 0; ch < 4; ++ch) {
        #pragma unroll 2
        for (int q = 0; q < 6; ++q) {
            int ntl = wv * 6 + q;               // 0..23 local tile (disjoint per wave)
            int c = (ch * 24 + ntl) * 16 + cl;
            int kk = c & 31, ii = c >> 5;
            const ushort_t* kbase = kb + (size_t)kk * 2304 + ii * 48;
            bf16x8 B0 = *reinterpret_cast<const bf16x8*>(kbase + g * 8);
            bf16x8 B1 = (g < 2) ? *reinterpret_cast<const bf16x8*>(kbase + 32 + g * 8) : zero8;
            #pragma unroll
            for (int mt = 0; mt < 2; ++mt) {
                f32x4 acc = {0.f, 0.f, 0.f, 0.f};
                acc = __builtin_amdgcn_mfma_f32_16x16x32_bf16(A[mt][0], B0, acc, 0, 0, 0);
                acc = __builtin_amdgcn_mfma_f32_16x16x32_bf16(A[mt][1], B1, acc, 0, 0, 0);
                #pragma unroll
                for (int r = 0; r < 4; ++r) {
                    sY[mt * 16 + g * 4 + r][ntl * 16 + cl] = f2bf(acc[r]);
                }
            }
        }
        __syncthreads();
        // coalesced store: 32 rows x 384 ushorts = 1536 x 16B chunks
        for (int idx = t; idx < 1536; idx += 256) {
            int row = idx / 48, c8 = idx % 48;
            int n = n0 + row;
            if (n < N_ATOMS) {
                *reinterpret_cast<uint4*>(Yb + (size_t)n * 1536 + ch * 384 + c8 * 8) =
                    *reinterpret_cast<const uint4*>(&sY[row][c8 * 8]);
            }
        }
        __syncthreads();
    }

    // Bn[n][i] = dot(bias[i*48..+48], amc[n])  (bf16 amc, f32 bias/accum)
    for (int idx = t; idx < 32 * 48; idx += 256) {
        int row = idx / 48, i = idx % 48;
        int n = n0 + row;
        if (n >= N_ATOMS) continue;
        const float* bb = bias + i * 48;
        float accv = 0.f;
        #pragma unroll
        for (int j = 0; j < 48; ++j) accv += bb[j] * bf2f(amcs[row][j]);
        Bn[(size_t)n * 48 + i] = accv;
    }
}

// ================= per-edge message + scatter (bf16 Y, vectorized) =================
// lane i in [0,48): reads Yp[dst][i*32 .. i*32+31] = 64 B contiguous (4x uint4)
__global__ __launch_bounds__(256) void edge_msg_k(const float* __restrict__ e_new,
                                                  const int* __restrict__ pair,
                                                  const ushort_t* __restrict__ Yb,
                                                  const float* __restrict__ Bn,
                                                  float* __restrict__ agg)
{
    int t = threadIdx.x;
    int lane = t & 63;
    int eid = blockIdx.x * 4 + (t >> 6);
    if (lane >= 48) return;
    int src = pair[2 * eid], dst = pair[2 * eid + 1];

    float ev[32];
    const float4* ep = reinterpret_cast<const float4*>(e_new + (size_t)eid * 32);
    #pragma unroll
    for (int q = 0; q < 8; ++q) {
        float4 v = ep[q];
        ev[4*q] = v.x; ev[4*q+1] = v.y; ev[4*q+2] = v.z; ev[4*q+3] = v.w;
    }

    const uint4* yp = reinterpret_cast<const uint4*>(Yb + (size_t)dst * 1536 + lane * 32);
    float acc = Bn[dst * 48 + lane];
    #pragma unroll
    for (int q = 0; q < 4; ++q) {
        uint4 v = yp[q];
        int k = q * 8;
        acc += bflo(v.x) * ev[k]     + bfhi(v.x) * ev[k + 1]
             + bflo(v.y) * ev[k + 2] + bfhi(v.y) * ev[k + 3]
             + bflo(v.z) * ev[k + 4] + bfhi(v.z) * ev[k + 5]
             + bflo(v.w) * ev[k + 6] + bfhi(v.w) * ev[k + 7];
    }
    atomicAdd(&agg[src * 48 + lane], acc);
}

// ================= fused node GRU: GEMM (S in LDS) + gates =================
// 16 nodes/block, 192 threads. asum via per-block sorted-agi reduction.
__global__ __launch_bounds__(192) void node_fused_k(const float* __restrict__ agg,
                                                    const float* __restrict__ a_in,
                                                    const float* __restrict__ wtn,
                                                    const float* __restrict__ wtun,
                                                    const float* __restrict__ bn_in,
                                                    const float* __restrict__ bn_rec,
                                                    const int* __restrict__ agi,
                                                    float* __restrict__ a_out,
                                                    float* __restrict__ asum)
{
    __shared__ float xs[16][48];
    __shared__ float hs[16][32];
    __shared__ float S[16][192];
    __shared__ int garr[16];
    int t = threadIdx.x;
    int n0 = blockIdx.x * 16;

    reinterpret_cast<float4*>(&xs[0][0])[t] =
        reinterpret_cast<const float4*>(agg + (size_t)n0 * 48)[t];       // 192 float4
    if (t < 128) reinterpret_cast<float4*>(&hs[0][0])[t] =
        reinterpret_cast<const float4*>(a_in + (size_t)n0 * 32)[t];
    if (t >= 128 && t < 144) garr[t - 128] = agi[n0 + (t - 128)];
    __syncthreads();

    if (t < 96) {
        float w[48];
        const float4* wp4 = reinterpret_cast<const float4*>(wtn + t * 48);
        #pragma unroll
        for (int q = 0; q < 12; ++q) {
            float4 v = wp4[q];
            w[4*q] = v.x; w[4*q+1] = v.y; w[4*q+2] = v.z; w[4*q+3] = v.w;
        }
        float b = bn_in[t];
        #pragma unroll 4
        for (int i = 0; i < 16; ++i) {
            float sres = b;
            #pragma unroll
            for (int k = 0; k < 48; ++k) sres += xs[i][k] * w[k];
            S[i][t] = sres;
        }
    } else {
        float w[32];
        const float4* wp4 = reinterpret_cast<const float4*>(wtun + (t - 96) * 32);
        #pragma unroll
        for (int q = 0; q < 8; ++q) {
            float4 v = wp4[q];
            w[4*q] = v.x; w[4*q+1] = v.y; w[4*q+2] = v.z; w[4*q+3] = v.w;
        }
        float b = bn_rec[t - 96];
        #pragma unroll 4
        for (int i = 0; i < 16; ++i) {
            float sres = b;
            #pragma unroll
            for (int k = 0; k < 32; ++k) sres += hs[i][k] * w[k];
            S[i][t] = sres;
        }
    }
    __syncthreads();

    for (int idx = t; idx < 512; idx += 192) {
        int le = idx >> 5, cc = idx & 31;
        int n = n0 + le;
        float z  = 1.f / (1.f + expf(-(S[le][cc] + S[le][96 + cc])));
        float r  = 1.f / (1.f + expf(-(S[le][32 + cc] + S[le][128 + cc])));
        float hc = tanhf(S[le][64 + cc] + r * S[le][160 + cc]);
        float h  = hs[le][cc];
        float val = z * h + (1.f - z) * hc;
        a_out[(size_t)n * 32 + cc] = val;
        hs[le][cc] = val;                       // stash for block-level asum reduction
    }
    __syncthreads();

    if (t < 32) {
        int cc = t;
        int gprev = garr[0];
        float run = 0.f;
        #pragma unroll 4
        for (int le = 0; le < 16; ++le) {
            int gcur = garr[le];                // wave-uniform
            if (gcur != gprev) {
                atomicAdd(&asum[gprev * 32 + cc], run);
                run = 0.f; gprev = gcur;
            }
            run += hs[le][cc];
        }
        atomicAdd(&asum[gprev * 32 + cc], run);
    }
}

// ================= state GRU =================
__global__ void state_gru_k(const float* __restrict__ asum, const float* __restrict__ esum,
                            const float* __restrict__ s_in,
                            const float* __restrict__ Ws, const float* __restrict__ Us,
                            const float* __restrict__ bs_in, const float* __restrict__ bs_rec,
                            float* __restrict__ s_out)
{
    __shared__ float xs[80];
    __shared__ float hsv[16];
    __shared__ float S[48];
    __shared__ float Uh[16];
    int g = blockIdx.x;
    int t = threadIdx.x;
    if (t < 80) {
        float v;
        if (t < 32)      v = asum[g * 32 + t];
        else if (t < 64) v = esum[g * 32 + (t - 32)];
        else             v = s_in[g * 16 + (t - 64)];
        xs[t] = v;
        if (t >= 64) hsv[t - 64] = v;
    }
    __syncthreads();
    if (t < 48) {
        float gacc = bs_in[t];
        #pragma unroll
        for (int k = 0; k < 80; ++k) gacc += xs[k] * Ws[k * 48 + t];
        float u = bs_rec[t];
        #pragma unroll
        for (int k = 0; k < 16; ++k) u += hsv[k] * Us[k * 48 + t];
        if (t < 32) { S[t] = gacc + u; }
        else        { S[t] = gacc; Uh[t - 32] = u; }
    }
    __syncthreads();
    if (t < 16) {
        float z  = 1.f / (1.f + expf(-S[t]));
        float r  = 1.f / (1.f + expf(-S[16 + t]));
        float hc = tanhf(S[32 + t] + r * Uh[t]);
        s_out[g * 16 + t] = z * hsv[t] + (1.f - z) * hc;
    }
}

extern "C" void kernel_launch(void* const* d_in, const int* in_sizes, int n_in,
                              void* d_out, int out_size, void* d_ws, size_t ws_size,
                              hipStream_t stream)
{
    const float* a0      = (const float*)d_in[0];
    const float* e0      = (const float*)d_in[1];
    const float* s0      = (const float*)d_in[2];
    const int*   pair    = (const int*)d_in[3];
    const int*   agi     = (const int*)d_in[4];
    const int*   bgi     = (const int*)d_in[5];
    const float* kernelw = (const float*)d_in[6];
    const float* bias    = (const float*)d_in[7];
    const float* We      = (const float*)d_in[8];
    const float* Ue      = (const float*)d_in[9];
    const float* be_in   = (const float*)d_in[10];
    const float* be_rec  = (const float*)d_in[11];
    const float* Wn      = (const float*)d_in[12];
    const float* Un      = (const float*)d_in[13];
    const float* bn_in   = (const float*)d_in[14];
    const float* bn_rec  = (const float*)d_in[15];
    const float* Ws      = (const float*)d_in[16];
    const float* Us      = (const float*)d_in[17];
    const float* bs_in   = (const float*)d_in[18];
    const float* bs_rec  = (const float*)d_in[19];

    float* out_a = (float*)d_out;                    // N*32
    float* out_e = out_a + N_ATOMS * 32;             // E*32
    float* out_s = out_e + (size_t)N_EDGES * 32;     // G*16

    char* wp = (char*)d_ws;
    auto alloc = [&](size_t nf) { float* p = (float*)wp; wp += nf * sizeof(float); return p; };
    float* aW   = alloc((size_t)N_ATOMS * 32);
    float* eW   = alloc((size_t)N_EDGES * 32);
    float* sW   = alloc((size_t)N_GRAPH * 16);
    ushort_t* Yb = (ushort_t*)alloc((size_t)N_ATOMS * 1536 / 2);  // bf16, 30.7 MB
    float* Bn   = alloc((size_t)N_ATOMS * 48);
    float* agg  = alloc((size_t)N_ATOMS * 48);       // agg..esum contiguous memset
    float* asum = alloc((size_t)N_GRAPH * 32);
    float* esum = alloc((size_t)N_GRAPH * 32);
    float* PA   = alloc((size_t)N_ATOMS * 192);
    float* PS   = alloc((size_t)N_GRAPH * 96);
    float* wta  = alloc(6144);
    float* wts  = alloc(1536);
    float* wtee = alloc(6144);
    float* wtn  = alloc(4608);
    float* wtun = alloc(3072);
    ushort_t* kb = (ushort_t*)alloc(36864);          // 73728 bf16 = kernel(32x2304)
    size_t zero_bytes = ((size_t)N_ATOMS * 48 + 2 * N_GRAPH * 32) * sizeof(float);

    trans_k<<<372, 256, 0, stream>>>(We, Ue, Wn, Un, kernelw,
                                     wta, wts, wtee, wtn, wtun, kb);

    const float* a_in = a0;
    const float* e_in = e0;
    const float* s_in = s0;

    for (int step = 0; step < 2; ++step) {
        float* a_o = (step == 0) ? aW : out_a;
        float* e_o = (step == 0) ? eW : out_e;
        float* s_o = (step == 0) ? sW : out_s;

        hipMemsetAsync(agg, 0, zero_bytes, stream);
        pa_k<<<N_ATOMS / 16, 192, 0, stream>>>(a_in, wta, PA);
        ps_k<<<N_GRAPH / 16, 96, 0, stream>>>(s_in, wts, be_in, PS);
        edge_fused_k<<<N_EDGES / 16, 192, 0, stream>>>(e_in, wtee, be_rec, PA, PS,
                                                       pair, bgi, e_o, esum);
        y_mfma_k<<<(N_ATOMS + 31) / 32, 256, 0, stream>>>(kb, bias, a_in, s_in, agi, Yb, Bn);
        edge_msg_k<<<N_EDGES / 4, 256, 0, stream>>>(e_o, pair, Yb, Bn, agg);
        node_fused_k<<<N_ATOMS / 16, 192, 0, stream>>>(agg, a_in, wtn, wtun,
                                                       bn_in, bn_rec, agi, a_o, asum);
        state_gru_k<<<N_GRAPH, 128, 0, stream>>>(asum, esum, s_in, Ws, Us, bs_in, bs_rec, s_o);

        a_in = a_o; e_in = e_o; s_in = s_o;
    }
}

// Round 17
// 309.003 us; speedup vs baseline: 1.0458x; 1.0253x over previous
//
#include <hip/hip_runtime.h>

// MEGNet-like message passing: N=10000 atoms, E=40000 edges, G=128 graphs
// ATOM=32, EDGE=32, STATE=16, D=48, STEPS=2
#define N_ATOMS 10000
#define N_EDGES 40000
#define N_GRAPH 128

typedef unsigned short ushort_t;
typedef __attribute__((ext_vector_type(8))) short bf16x8;
typedef __attribute__((ext_vector_type(4))) float f32x4;

__device__ __forceinline__ ushort_t f2bf(float f) {
    unsigned int u = __float_as_uint(f);
    unsigned int r = (u + 0x7fffu + ((u >> 16) & 1u)) >> 16;   // RNE
    return (ushort_t)r;
}
__device__ __forceinline__ float bf2f(ushort_t u) { return __uint_as_float(((unsigned int)u) << 16); }
__device__ __forceinline__ float bflo(unsigned int u) { return __uint_as_float(u << 16); }
__device__ __forceinline__ float bfhi(unsigned int u) { return __uint_as_float(u & 0xffff0000u); }

// ================= weight transpose/pack (once per launch) =================
__global__ void trans_k(const float* __restrict__ We, const float* __restrict__ Ue,
                        const float* __restrict__ Wn, const float* __restrict__ Un,
                        const float* __restrict__ kernelw,
                        float* __restrict__ wta, float* __restrict__ wts,
                        float* __restrict__ wtee, float* __restrict__ wtn,
                        float* __restrict__ wtun, ushort_t* __restrict__ kb)
{
    int idx = blockIdx.x * 256 + threadIdx.x;   // 372*256 = 95232 exact
    if (idx < 6144) {
        int c = idx / 32, k = idx % 32;
        int col = c % 96;
        int srck = (c < 96) ? k : 32 + k;
        wta[idx] = We[srck * 96 + col];
    } else if (idx < 7680) {
        int j = idx - 6144; int c = j / 16, k = j % 16;
        wts[j] = We[(64 + k) * 96 + c];
    } else if (idx < 13824) {
        int j = idx - 7680; int c = j / 32, k = j % 32;
        wtee[j] = (c < 96) ? We[(80 + k) * 96 + c] : Ue[k * 96 + (c - 96)];
    } else if (idx < 18432) {
        int j = idx - 13824; int c = j / 48, k = j % 48;
        wtn[j] = Wn[k * 96 + c];
    } else if (idx < 21504) {
        int j = idx - 18432; int c = j / 32, k = j % 32;
        wtun[j] = Un[k * 96 + c];
    } else {
        int j = idx - 21504;                    // 0 .. 73727
        kb[j] = f2bf(kernelw[j]);
    }
}

// ================= fused PA + PS precompute =================
// blocks [0, N/16): PA[n][c] = a[n] . WTa[c]            (c in [0,192), 192 thr)
// blocks [N/16, N/16+G/16): PS[g][c] = s[g].WTs[c]+be_in (c in [0,96), 96 thr active)
__global__ __launch_bounds__(192) void pa_ps_k(const float* __restrict__ a,
                                               const float* __restrict__ wta,
                                               float* __restrict__ PA,
                                               const float* __restrict__ s,
                                               const float* __restrict__ wts,
                                               const float* __restrict__ be_in,
                                               float* __restrict__ PS)
{
    __shared__ float as_[16][32];
    __shared__ float ss[16][16];
    int t = threadIdx.x;

    if (blockIdx.x < N_ATOMS / 16) {
        int n0 = blockIdx.x * 16;
        if (t < 128) reinterpret_cast<float4*>(&as_[0][0])[t] =
            reinterpret_cast<const float4*>(a + (size_t)n0 * 32)[t];
        __syncthreads();

        float w[32];
        const float4* wp4 = reinterpret_cast<const float4*>(wta + t * 32);
        #pragma unroll
        for (int q = 0; q < 8; ++q) {
            float4 v = wp4[q];
            w[4*q] = v.x; w[4*q+1] = v.y; w[4*q+2] = v.z; w[4*q+3] = v.w;
        }
        #pragma unroll
        for (int i = 0; i < 16; ++i) {
            float sres = 0.f;
            #pragma unroll
            for (int k = 0; k < 32; ++k) sres += as_[i][k] * w[k];
            PA[(size_t)(n0 + i) * 192 + t] = sres;
        }
    } else {
        int g0 = (blockIdx.x - N_ATOMS / 16) * 16;
        if (t < 64) reinterpret_cast<float4*>(&ss[0][0])[t] =
            reinterpret_cast<const float4*>(s + (size_t)g0 * 16)[t];
        __syncthreads();
        if (t < 96) {
            float w[16];
            const float4* wp4 = reinterpret_cast<const float4*>(wts + t * 16);
            #pragma unroll
            for (int q = 0; q < 4; ++q) {
                float4 v = wp4[q];
                w[4*q] = v.x; w[4*q+1] = v.y; w[4*q+2] = v.z; w[4*q+3] = v.w;
            }
            float b = be_in[t];
            #pragma unroll
            for (int i = 0; i < 16; ++i) {
                float sres = b;
                #pragma unroll
                for (int k = 0; k < 16; ++k) sres += ss[i][k] * w[k];
                PS[(size_t)(g0 + i) * 96 + t] = sres;
            }
        }
    }
}

// ================= fused edge GRU: per-edge GEMM (S in LDS) + gates =================
// 16 edges/block, 192 threads. esum via per-block sorted-bgi reduction.
__global__ __launch_bounds__(192) void edge_fused_k(const float* __restrict__ e_in,
                                                    const float* __restrict__ wtee,
                                                    const float* __restrict__ be_rec,
                                                    const float* __restrict__ PA,
                                                    const float* __restrict__ PS,
                                                    const int* __restrict__ pair,
                                                    const int* __restrict__ bgi,
                                                    float* __restrict__ e_out,
                                                    float* __restrict__ esum)
{
    __shared__ float es[16][32];
    __shared__ float S[16][192];
    __shared__ int garr[16];
    int t = threadIdx.x;
    int e0b = blockIdx.x * 16;

    if (t < 128) reinterpret_cast<float4*>(&es[0][0])[t] =
        reinterpret_cast<const float4*>(e_in + (size_t)e0b * 32)[t];
    if (t >= 128 && t < 144) garr[t - 128] = bgi[e0b + (t - 128)];
    __syncthreads();

    float w[32];
    const float4* wp4 = reinterpret_cast<const float4*>(wtee + t * 32);
    #pragma unroll
    for (int q = 0; q < 8; ++q) {
        float4 v = wp4[q];
        w[4*q] = v.x; w[4*q+1] = v.y; w[4*q+2] = v.z; w[4*q+3] = v.w;
    }
    float b = (t >= 96) ? be_rec[t - 96] : 0.f;
    #pragma unroll 4
    for (int i = 0; i < 16; ++i) {
        float sres = b;
        #pragma unroll
        for (int k = 0; k < 32; ++k) sres += es[i][k] * w[k];
        S[i][t] = sres;
    }
    __syncthreads();

    for (int idx = t; idx < 512; idx += 192) {
        int le = idx >> 5, cc = idx & 31;
        int eid = e0b + le;
        int src = pair[2 * eid], dst = pair[2 * eid + 1];
        const float* pas = PA + (size_t)src * 192;
        const float* pad = PA + (size_t)dst * 192 + 96;
        const float* ps  = PS + (size_t)garr[le] * 96;
        float xz = pas[cc]      + pad[cc]      + ps[cc]      + S[le][cc];
        float xr = pas[32 + cc] + pad[32 + cc] + ps[32 + cc] + S[le][32 + cc];
        float xh = pas[64 + cc] + pad[64 + cc] + ps[64 + cc] + S[le][64 + cc];
        float hz = S[le][96 + cc], hr = S[le][128 + cc], hh = S[le][160 + cc];
        float h  = es[le][cc];
        float z  = 1.f / (1.f + expf(-(xz + hz)));
        float r  = 1.f / (1.f + expf(-(xr + hr)));
        float hc = tanhf(xh + r * hh);
        float val = z * h + (1.f - z) * hc;
        e_out[(size_t)eid * 32 + cc] = val;
        es[le][cc] = val;                       // stash for block-level esum reduction
    }
    __syncthreads();

    if (t < 32) {
        int cc = t;
        int gprev = garr[0];
        float run = 0.f;
        #pragma unroll 4
        for (int le = 0; le < 16; ++le) {
            int gcur = garr[le];                // wave-uniform
            if (gcur != gprev) {
                atomicAdd(&esum[gprev * 32 + cc], run);
                run = 0.f; gprev = gcur;
            }
            run += es[le][cc];
        }
        atomicAdd(&esum[gprev * 32 + cc], run);
    }
}

// ================= Y via MFMA (round-13 measured-best version) =================
__global__ __launch_bounds__(256) void y_mfma_k(const ushort_t* __restrict__ kb,
                                                const float* __restrict__ bias,
                                                const float* __restrict__ a,
                                                const float* __restrict__ s,
                                                const int* __restrict__ agi,
                                                ushort_t* __restrict__ Yb,
                                                float* __restrict__ Bn)
{
    __shared__ ushort_t amcs[32][64];
    int t = threadIdx.x;
    int n0 = blockIdx.x * 32;

    for (int idx = t; idx < 32 * 64; idx += 256) {
        int row = idx >> 6, j = idx & 63;
        int n = n0 + row;
        float v = 0.f;
        if (n < N_ATOMS) {
            if (j < 32)      v = a[(size_t)n * 32 + j];
            else if (j < 48) v = s[agi[n] * 16 + (j - 32)];
        }
        amcs[row][j] = f2bf(v);
    }
    __syncthreads();

    int lane = t & 63;
    int wv = t >> 6;
    int cl = lane & 15;
    int g  = lane >> 4;

    bf16x8 zero8 = {0, 0, 0, 0, 0, 0, 0, 0};

    bf16x8 A[2][2];
    #pragma unroll
    for (int mt = 0; mt < 2; ++mt) {
        #pragma unroll
        for (int kh = 0; kh < 2; ++kh) {
            A[mt][kh] = *reinterpret_cast<const bf16x8*>(&amcs[mt * 16 + cl][kh * 32 + g * 8]);
        }
    }

    for (int nt = wv; nt < 96; nt += 4) {
        int c = nt * 16 + cl;
        int kk = c & 31, ii = c >> 5;
        const ushort_t* kbase = kb + (size_t)kk * 2304 + ii * 48;
        bf16x8 B0 = *reinterpret_cast<const bf16x8*>(kbase + g * 8);
        bf16x8 B1 = (g < 2) ? *reinterpret_cast<const bf16x8*>(kbase + 32 + g * 8) : zero8;
        #pragma unroll
        for (int mt = 0; mt < 2; ++mt) {
            f32x4 acc = {0.f, 0.f, 0.f, 0.f};
            acc = __builtin_amdgcn_mfma_f32_16x16x32_bf16(A[mt][0], B0, acc, 0, 0, 0);
            acc = __builtin_amdgcn_mfma_f32_16x16x32_bf16(A[mt][1], B1, acc, 0, 0, 0);
            #pragma unroll
            for (int r = 0; r < 4; ++r) {
                int n = n0 + mt * 16 + g * 4 + r;
                if (n < N_ATOMS) Yb[(size_t)n * 1536 + c] = f2bf(acc[r]);
            }
        }
    }

    // Bn[n][i] = dot(bias[i*48..+48], amc[n])  (bf16 amc, f32 bias/accum)
    for (int idx = t; idx < 32 * 48; idx += 256) {
        int row = idx / 48, i = idx % 48;
        int n = n0 + row;
        if (n >= N_ATOMS) continue;
        const float* bb = bias + i * 48;
        float accv = 0.f;
        #pragma unroll
        for (int j = 0; j < 48; ++j) accv += bb[j] * bf2f(amcs[row][j]);
        Bn[(size_t)n * 48 + i] = accv;
    }
}

// ================= per-edge message + scatter (bf16 Y, vectorized) =================
// lane i in [0,48): reads Yp[dst][i*32 .. i*32+31] = 64 B contiguous (4x uint4)
__global__ __launch_bounds__(256) void edge_msg_k(const float* __restrict__ e_new,
                                                  const int* __restrict__ pair,
                                                  const ushort_t* __restrict__ Yb,
                                                  const float* __restrict__ Bn,
                                                  float* __restrict__ agg)
{
    int t = threadIdx.x;
    int lane = t & 63;
    int eid = blockIdx.x * 4 + (t >> 6);
    if (lane >= 48) return;
    int src = pair[2 * eid], dst = pair[2 * eid + 1];

    float ev[32];
    const float4* ep = reinterpret_cast<const float4*>(e_new + (size_t)eid * 32);
    #pragma unroll
    for (int q = 0; q < 8; ++q) {
        float4 v = ep[q];
        ev[4*q] = v.x; ev[4*q+1] = v.y; ev[4*q+2] = v.z; ev[4*q+3] = v.w;
    }

    const uint4* yp = reinterpret_cast<const uint4*>(Yb + (size_t)dst * 1536 + lane * 32);
    float acc = Bn[dst * 48 + lane];
    #pragma unroll
    for (int q = 0; q < 4; ++q) {
        uint4 v = yp[q];
        int k = q * 8;
        acc += bflo(v.x) * ev[k]     + bfhi(v.x) * ev[k + 1]
             + bflo(v.y) * ev[k + 2] + bfhi(v.y) * ev[k + 3]
             + bflo(v.z) * ev[k + 4] + bfhi(v.z) * ev[k + 5]
             + bflo(v.w) * ev[k + 6] + bfhi(v.w) * ev[k + 7];
    }
    atomicAdd(&agg[src * 48 + lane], acc);
}

// ================= fused node GRU: GEMM (S in LDS) + gates =================
// 16 nodes/block, 192 threads. asum via per-block sorted-agi reduction.
__global__ __launch_bounds__(192) void node_fused_k(const float* __restrict__ agg,
                                                    const float* __restrict__ a_in,
                                                    const float* __restrict__ wtn,
                                                    const float* __restrict__ wtun,
                                                    const float* __restrict__ bn_in,
                                                    const float* __restrict__ bn_rec,
                                                    const int* __restrict__ agi,
                                                    float* __restrict__ a_out,
                                                    float* __restrict__ asum)
{
    __shared__ float xs[16][48];
    __shared__ float hs[16][32];
    __shared__ float S[16][192];
    __shared__ int garr[16];
    int t = threadIdx.x;
    int n0 = blockIdx.x * 16;

    reinterpret_cast<float4*>(&xs[0][0])[t] =
        reinterpret_cast<const float4*>(agg + (size_t)n0 * 48)[t];       // 192 float4
    if (t < 128) reinterpret_cast<float4*>(&hs[0][0])[t] =
        reinterpret_cast<const float4*>(a_in + (size_t)n0 * 32)[t];
    if (t >= 128 && t < 144) garr[t - 128] = agi[n0 + (t - 128)];
    __syncthreads();

    if (t < 96) {
        float w[48];
        const float4* wp4 = reinterpret_cast<const float4*>(wtn + t * 48);
        #pragma unroll
        for (int q = 0; q < 12; ++q) {
            float4 v = wp4[q];
            w[4*q] = v.x; w[4*q+1] = v.y; w[4*q+2] = v.z; w[4*q+3] = v.w;
        }
        float b = bn_in[t];
        #pragma unroll 4
        for (int i = 0; i < 16; ++i) {
            float sres = b;
            #pragma unroll
            for (int k = 0; k < 48; ++k) sres += xs[i][k] * w[k];
            S[i][t] = sres;
        }
    } else {
        float w[32];
        const float4* wp4 = reinterpret_cast<const float4*>(wtun + (t - 96) * 32);
        #pragma unroll
        for (int q = 0; q < 8; ++q) {
            float4 v = wp4[q];
            w[4*q] = v.x; w[4*q+1] = v.y; w[4*q+2] = v.z; w[4*q+3] = v.w;
        }
        float b = bn_rec[t - 96];
        #pragma unroll 4
        for (int i = 0; i < 16; ++i) {
            float sres = b;
            #pragma unroll
            for (int k = 0; k < 32; ++k) sres += hs[i][k] * w[k];
            S[i][t] = sres;
        }
    }
    __syncthreads();

    for (int idx = t; idx < 512; idx += 192) {
        int le = idx >> 5, cc = idx & 31;
        int n = n0 + le;
        float z  = 1.f / (1.f + expf(-(S[le][cc] + S[le][96 + cc])));
        float r  = 1.f / (1.f + expf(-(S[le][32 + cc] + S[le][128 + cc])));
        float hc = tanhf(S[le][64 + cc] + r * S[le][160 + cc]);
        float h  = hs[le][cc];
        float val = z * h + (1.f - z) * hc;
        a_out[(size_t)n * 32 + cc] = val;
        hs[le][cc] = val;                       // stash for block-level asum reduction
    }
    __syncthreads();

    if (t < 32) {
        int cc = t;
        int gprev = garr[0];
        float run = 0.f;
        #pragma unroll 4
        for (int le = 0; le < 16; ++le) {
            int gcur = garr[le];                // wave-uniform
            if (gcur != gprev) {
                atomicAdd(&asum[gprev * 32 + cc], run);
                run = 0.f; gprev = gcur;
            }
            run += hs[le][cc];
        }
        atomicAdd(&asum[gprev * 32 + cc], run);
    }
}

// ================= state GRU =================
__global__ void state_gru_k(const float* __restrict__ asum, const float* __restrict__ esum,
                            const float* __restrict__ s_in,
                            const float* __restrict__ Ws, const float* __restrict__ Us,
                            const float* __restrict__ bs_in, const float* __restrict__ bs_rec,
                            float* __restrict__ s_out)
{
    __shared__ float xs[80];
    __shared__ float hsv[16];
    __shared__ float S[48];
    __shared__ float Uh[16];
    int g = blockIdx.x;
    int t = threadIdx.x;
    if (t < 80) {
        float v;
        if (t < 32)      v = asum[g * 32 + t];
        else if (t < 64) v = esum[g * 32 + (t - 32)];
        else             v = s_in[g * 16 + (t - 64)];
        xs[t] = v;
        if (t >= 64) hsv[t - 64] = v;
    }
    __syncthreads();
    if (t < 48) {
        float gacc = bs_in[t];
        #pragma unroll
        for (int k = 0; k < 80; ++k) gacc += xs[k] * Ws[k * 48 + t];
        float u = bs_rec[t];
        #pragma unroll
        for (int k = 0; k < 16; ++k) u += hsv[k] * Us[k * 48 + t];
        if (t < 32) { S[t] = gacc + u; }
        else        { S[t] = gacc; Uh[t - 32] = u; }
    }
    __syncthreads();
    if (t < 16) {
        float z  = 1.f / (1.f + expf(-S[t]));
        float r  = 1.f / (1.f + expf(-S[16 + t]));
        float hc = tanhf(S[32 + t] + r * Uh[t]);
        s_out[g * 16 + t] = z * hsv[t] + (1.f - z) * hc;
    }
}

extern "C" void kernel_launch(void* const* d_in, const int* in_sizes, int n_in,
                              void* d_out, int out_size, void* d_ws, size_t ws_size,
                              hipStream_t stream)
{
    const float* a0      = (const float*)d_in[0];
    const float* e0      = (const float*)d_in[1];
    const float* s0      = (const float*)d_in[2];
    const int*   pair    = (const int*)d_in[3];
    const int*   agi     = (const int*)d_in[4];
    const int*   bgi     = (const int*)d_in[5];
    const float* kernelw = (const float*)d_in[6];
    const float* bias    = (const float*)d_in[7];
    const float* We      = (const float*)d_in[8];
    const float* Ue      = (const float*)d_in[9];
    const float* be_in   = (const float*)d_in[10];
    const float* be_rec  = (const float*)d_in[11];
    const float* Wn      = (const float*)d_in[12];
    const float* Un      = (const float*)d_in[13];
    const float* bn_in   = (const float*)d_in[14];
    const float* bn_rec  = (const float*)d_in[15];
    const float* Ws      = (const float*)d_in[16];
    const float* Us      = (const float*)d_in[17];
    const float* bs_in   = (const float*)d_in[18];
    const float* bs_rec  = (const float*)d_in[19];

    float* out_a = (float*)d_out;                    // N*32
    float* out_e = out_a + N_ATOMS * 32;             // E*32
    float* out_s = out_e + (size_t)N_EDGES * 32;     // G*16

    char* wp = (char*)d_ws;
    auto alloc = [&](size_t nf) { float* p = (float*)wp; wp += nf * sizeof(float); return p; };
    float* aW   = alloc((size_t)N_ATOMS * 32);
    float* eW   = alloc((size_t)N_EDGES * 32);
    float* sW   = alloc((size_t)N_GRAPH * 16);
    ushort_t* Yb = (ushort_t*)alloc((size_t)N_ATOMS * 1536 / 2);  // bf16, 30.7 MB
    float* Bn   = alloc((size_t)N_ATOMS * 48);
    float* agg  = alloc((size_t)N_ATOMS * 48);       // agg..esum contiguous memset
    float* asum = alloc((size_t)N_GRAPH * 32);
    float* esum = alloc((size_t)N_GRAPH * 32);
    float* PA   = alloc((size_t)N_ATOMS * 192);
    float* PS   = alloc((size_t)N_GRAPH * 96);
    float* wta  = alloc(6144);
    float* wts  = alloc(1536);
    float* wtee = alloc(6144);
    float* wtn  = alloc(4608);
    float* wtun = alloc(3072);
    ushort_t* kb = (ushort_t*)alloc(36864);          // 73728 bf16 = kernel(32x2304)
    size_t zero_bytes = ((size_t)N_ATOMS * 48 + 2 * N_GRAPH * 32) * sizeof(float);

    trans_k<<<372, 256, 0, stream>>>(We, Ue, Wn, Un, kernelw,
                                     wta, wts, wtee, wtn, wtun, kb);

    const float* a_in = a0;
    const float* e_in = e0;
    const float* s_in = s0;

    for (int step = 0; step < 2; ++step) {
        float* a_o = (step == 0) ? aW : out_a;
        float* e_o = (step == 0) ? eW : out_e;
        float* s_o = (step == 0) ? sW : out_s;

        hipMemsetAsync(agg, 0, zero_bytes, stream);
        pa_ps_k<<<N_ATOMS / 16 + N_GRAPH / 16, 192, 0, stream>>>(a_in, wta, PA,
                                                                 s_in, wts, be_in, PS);
        edge_fused_k<<<N_EDGES / 16, 192, 0, stream>>>(e_in, wtee, be_rec, PA, PS,
                                                       pair, bgi, e_o, esum);
        y_mfma_k<<<(N_ATOMS + 31) / 32, 256, 0, stream>>>(kb, bias, a_in, s_in, agi, Yb, Bn);
        edge_msg_k<<<N_EDGES / 4, 256, 0, stream>>>(e_o, pair, Yb, Bn, agg);
        node_fused_k<<<N_ATOMS / 16, 192, 0, stream>>>(agg, a_in, wtn, wtun,
                                                       bn_in, bn_rec, agi, a_o, asum);
        state_gru_k<<<N_GRAPH, 128, 0, stream>>>(asum, esum, s_in, Ws, Us, bs_in, bs_rec, s_o);

        a_in = a_o; e_in = e_o; s_in = s_o;
    }
}

// Round 18
// 297.193 us; speedup vs baseline: 1.0873x; 1.0397x over previous
//
#include <hip/hip_runtime.h>

// MEGNet-like message passing: N=10000 atoms, E=40000 edges, G=128 graphs
// ATOM=32, EDGE=32, STATE=16, D=48, STEPS=2
#define N_ATOMS 10000
#define N_EDGES 40000
#define N_GRAPH 128

typedef unsigned short ushort_t;
typedef __attribute__((ext_vector_type(8))) short bf16x8;
typedef __attribute__((ext_vector_type(4))) float f32x4;

__device__ __forceinline__ ushort_t f2bf(float f) {
    unsigned int u = __float_as_uint(f);
    unsigned int r = (u + 0x7fffu + ((u >> 16) & 1u)) >> 16;   // RNE
    return (ushort_t)r;
}
__device__ __forceinline__ float bf2f(ushort_t u) { return __uint_as_float(((unsigned int)u) << 16); }
__device__ __forceinline__ float bflo(unsigned int u) { return __uint_as_float(u << 16); }
__device__ __forceinline__ float bfhi(unsigned int u) { return __uint_as_float(u & 0xffff0000u); }

// ================= weight transpose/pack (once per launch) =================
__global__ void trans_k(const float* __restrict__ We, const float* __restrict__ Ue,
                        const float* __restrict__ Wn, const float* __restrict__ Un,
                        const float* __restrict__ kernelw,
                        float* __restrict__ wta, float* __restrict__ wts,
                        float* __restrict__ wtee, float* __restrict__ wtn,
                        float* __restrict__ wtun, ushort_t* __restrict__ kb)
{
    int idx = blockIdx.x * 256 + threadIdx.x;   // 372*256 = 95232 exact
    if (idx < 6144) {
        int c = idx / 32, k = idx % 32;
        int col = c % 96;
        int srck = (c < 96) ? k : 32 + k;
        wta[idx] = We[srck * 96 + col];
    } else if (idx < 7680) {
        int j = idx - 6144; int c = j / 16, k = j % 16;
        wts[j] = We[(64 + k) * 96 + c];
    } else if (idx < 13824) {
        int j = idx - 7680; int c = j / 32, k = j % 32;
        wtee[j] = (c < 96) ? We[(80 + k) * 96 + c] : Ue[k * 96 + (c - 96)];
    } else if (idx < 18432) {
        int j = idx - 13824; int c = j / 48, k = j % 48;
        wtn[j] = Wn[k * 96 + c];
    } else if (idx < 21504) {
        int j = idx - 18432; int c = j / 32, k = j % 32;
        wtun[j] = Un[k * 96 + c];
    } else {
        int j = idx - 21504;                    // 0 .. 73727
        kb[j] = f2bf(kernelw[j]);
    }
}

// ================= fused PA + PS precompute =================
__global__ __launch_bounds__(192) void pa_ps_k(const float* __restrict__ a,
                                               const float* __restrict__ wta,
                                               float* __restrict__ PA,
                                               const float* __restrict__ s,
                                               const float* __restrict__ wts,
                                               const float* __restrict__ be_in,
                                               float* __restrict__ PS)
{
    __shared__ float as_[16][32];
    __shared__ float ss[16][16];
    int t = threadIdx.x;

    if (blockIdx.x < N_ATOMS / 16) {
        int n0 = blockIdx.x * 16;
        if (t < 128) reinterpret_cast<float4*>(&as_[0][0])[t] =
            reinterpret_cast<const float4*>(a + (size_t)n0 * 32)[t];
        __syncthreads();

        float w[32];
        const float4* wp4 = reinterpret_cast<const float4*>(wta + t * 32);
        #pragma unroll
        for (int q = 0; q < 8; ++q) {
            float4 v = wp4[q];
            w[4*q] = v.x; w[4*q+1] = v.y; w[4*q+2] = v.z; w[4*q+3] = v.w;
        }
        #pragma unroll
        for (int i = 0; i < 16; ++i) {
            float sres = 0.f;
            #pragma unroll
            for (int k = 0; k < 32; ++k) sres += as_[i][k] * w[k];
            PA[(size_t)(n0 + i) * 192 + t] = sres;
        }
    } else {
        int g0 = (blockIdx.x - N_ATOMS / 16) * 16;
        if (t < 64) reinterpret_cast<float4*>(&ss[0][0])[t] =
            reinterpret_cast<const float4*>(s + (size_t)g0 * 16)[t];
        __syncthreads();
        if (t < 96) {
            float w[16];
            const float4* wp4 = reinterpret_cast<const float4*>(wts + t * 16);
            #pragma unroll
            for (int q = 0; q < 4; ++q) {
                float4 v = wp4[q];
                w[4*q] = v.x; w[4*q+1] = v.y; w[4*q+2] = v.z; w[4*q+3] = v.w;
            }
            float b = be_in[t];
            #pragma unroll
            for (int i = 0; i < 16; ++i) {
                float sres = b;
                #pragma unroll
                for (int k = 0; k < 16; ++k) sres += ss[i][k] * w[k];
                PS[(size_t)(g0 + i) * 96 + t] = sres;
            }
        }
    }
}

// ================= merged mid-pipeline: edge GRU  ||  Y-MFMA =================
// blocks [0, E/16): edge_fused work (256 thr; GEMM phase uses t<192)
// blocks [E/16, E/16 + ceil(N/32)): y_mfma work
#define NEB (N_EDGES / 16)
__global__ __launch_bounds__(256) void mid_k(const float* __restrict__ e_in,
                                             const float* __restrict__ wtee,
                                             const float* __restrict__ be_rec,
                                             const float* __restrict__ PA,
                                             const float* __restrict__ PS,
                                             const int* __restrict__ pair,
                                             const int* __restrict__ bgi,
                                             float* __restrict__ e_out,
                                             float* __restrict__ esum,
                                             const ushort_t* __restrict__ kb,
                                             const float* __restrict__ bias,
                                             const float* __restrict__ a,
                                             const float* __restrict__ s,
                                             const int* __restrict__ agi,
                                             ushort_t* __restrict__ Yb,
                                             float* __restrict__ Bn)
{
    int t = threadIdx.x;

    if (blockIdx.x < NEB) {
        // ---------------- edge_fused branch ----------------
        __shared__ float es[16][32];
        __shared__ float S[16][192];
        __shared__ int garr[16];
        int e0b = blockIdx.x * 16;

        if (t < 128) reinterpret_cast<float4*>(&es[0][0])[t] =
            reinterpret_cast<const float4*>(e_in + (size_t)e0b * 32)[t];
        if (t >= 128 && t < 144) garr[t - 128] = bgi[e0b + (t - 128)];
        __syncthreads();

        if (t < 192) {
            float w[32];
            const float4* wp4 = reinterpret_cast<const float4*>(wtee + t * 32);
            #pragma unroll
            for (int q = 0; q < 8; ++q) {
                float4 v = wp4[q];
                w[4*q] = v.x; w[4*q+1] = v.y; w[4*q+2] = v.z; w[4*q+3] = v.w;
            }
            float b = (t >= 96) ? be_rec[t - 96] : 0.f;
            #pragma unroll 4
            for (int i = 0; i < 16; ++i) {
                float sres = b;
                #pragma unroll
                for (int k = 0; k < 32; ++k) sres += es[i][k] * w[k];
                S[i][t] = sres;
            }
        }
        __syncthreads();

        for (int idx = t; idx < 512; idx += 256) {
            int le = idx >> 5, cc = idx & 31;
            int eid = e0b + le;
            int src = pair[2 * eid], dst = pair[2 * eid + 1];
            const float* pas = PA + (size_t)src * 192;
            const float* pad = PA + (size_t)dst * 192 + 96;
            const float* ps  = PS + (size_t)garr[le] * 96;
            float xz = pas[cc]      + pad[cc]      + ps[cc]      + S[le][cc];
            float xr = pas[32 + cc] + pad[32 + cc] + ps[32 + cc] + S[le][32 + cc];
            float xh = pas[64 + cc] + pad[64 + cc] + ps[64 + cc] + S[le][64 + cc];
            float hz = S[le][96 + cc], hr = S[le][128 + cc], hh = S[le][160 + cc];
            float h  = es[le][cc];
            float z  = 1.f / (1.f + expf(-(xz + hz)));
            float r  = 1.f / (1.f + expf(-(xr + hr)));
            float hc = tanhf(xh + r * hh);
            float val = z * h + (1.f - z) * hc;
            e_out[(size_t)eid * 32 + cc] = val;
            es[le][cc] = val;                   // stash for block-level esum reduction
        }
        __syncthreads();

        if (t < 32) {
            int cc = t;
            int gprev = garr[0];
            float run = 0.f;
            #pragma unroll 4
            for (int le = 0; le < 16; ++le) {
                int gcur = garr[le];            // wave-uniform
                if (gcur != gprev) {
                    atomicAdd(&esum[gprev * 32 + cc], run);
                    run = 0.f; gprev = gcur;
                }
                run += es[le][cc];
            }
            atomicAdd(&esum[gprev * 32 + cc], run);
        }
    } else {
        // ---------------- y_mfma branch ----------------
        __shared__ ushort_t amcs[32][64];
        int n0 = (blockIdx.x - NEB) * 32;

        for (int idx = t; idx < 32 * 64; idx += 256) {
            int row = idx >> 6, j = idx & 63;
            int n = n0 + row;
            float v = 0.f;
            if (n < N_ATOMS) {
                if (j < 32)      v = a[(size_t)n * 32 + j];
                else if (j < 48) v = s[agi[n] * 16 + (j - 32)];
            }
            amcs[row][j] = f2bf(v);
        }
        __syncthreads();

        int lane = t & 63;
        int wv = t >> 6;
        int cl = lane & 15;
        int g  = lane >> 4;

        bf16x8 zero8 = {0, 0, 0, 0, 0, 0, 0, 0};

        bf16x8 A[2][2];
        #pragma unroll
        for (int mt = 0; mt < 2; ++mt) {
            #pragma unroll
            for (int kh = 0; kh < 2; ++kh) {
                A[mt][kh] = *reinterpret_cast<const bf16x8*>(&amcs[mt * 16 + cl][kh * 32 + g * 8]);
            }
        }

        for (int nt = wv; nt < 96; nt += 4) {
            int c = nt * 16 + cl;
            int kk = c & 31, ii = c >> 5;
            const ushort_t* kbase = kb + (size_t)kk * 2304 + ii * 48;
            bf16x8 B0 = *reinterpret_cast<const bf16x8*>(kbase + g * 8);
            bf16x8 B1 = (g < 2) ? *reinterpret_cast<const bf16x8*>(kbase + 32 + g * 8) : zero8;
            #pragma unroll
            for (int mt = 0; mt < 2; ++mt) {
                f32x4 acc = {0.f, 0.f, 0.f, 0.f};
                acc = __builtin_amdgcn_mfma_f32_16x16x32_bf16(A[mt][0], B0, acc, 0, 0, 0);
                acc = __builtin_amdgcn_mfma_f32_16x16x32_bf16(A[mt][1], B1, acc, 0, 0, 0);
                #pragma unroll
                for (int r = 0; r < 4; ++r) {
                    int n = n0 + mt * 16 + g * 4 + r;
                    if (n < N_ATOMS) Yb[(size_t)n * 1536 + c] = f2bf(acc[r]);
                }
            }
        }

        for (int idx = t; idx < 32 * 48; idx += 256) {
            int row = idx / 48, i = idx % 48;
            int n = n0 + row;
            if (n >= N_ATOMS) continue;
            const float* bb = bias + i * 48;
            float accv = 0.f;
            #pragma unroll
            for (int j = 0; j < 48; ++j) accv += bb[j] * bf2f(amcs[row][j]);
            Bn[(size_t)n * 48 + i] = accv;
        }
    }
}

// ================= per-edge message + scatter (bf16 Y, vectorized) =================
__global__ __launch_bounds__(256) void edge_msg_k(const float* __restrict__ e_new,
                                                  const int* __restrict__ pair,
                                                  const ushort_t* __restrict__ Yb,
                                                  const float* __restrict__ Bn,
                                                  float* __restrict__ agg)
{
    int t = threadIdx.x;
    int lane = t & 63;
    int eid = blockIdx.x * 4 + (t >> 6);
    if (lane >= 48) return;
    int src = pair[2 * eid], dst = pair[2 * eid + 1];

    float ev[32];
    const float4* ep = reinterpret_cast<const float4*>(e_new + (size_t)eid * 32);
    #pragma unroll
    for (int q = 0; q < 8; ++q) {
        float4 v = ep[q];
        ev[4*q] = v.x; ev[4*q+1] = v.y; ev[4*q+2] = v.z; ev[4*q+3] = v.w;
    }

    const uint4* yp = reinterpret_cast<const uint4*>(Yb + (size_t)dst * 1536 + lane * 32);
    float acc = Bn[dst * 48 + lane];
    #pragma unroll
    for (int q = 0; q < 4; ++q) {
        uint4 v = yp[q];
        int k = q * 8;
        acc += bflo(v.x) * ev[k]     + bfhi(v.x) * ev[k + 1]
             + bflo(v.y) * ev[k + 2] + bfhi(v.y) * ev[k + 3]
             + bflo(v.z) * ev[k + 4] + bfhi(v.z) * ev[k + 5]
             + bflo(v.w) * ev[k + 6] + bfhi(v.w) * ev[k + 7];
    }
    atomicAdd(&agg[src * 48 + lane], acc);
}

// ================= fused node GRU: GEMM (S in LDS) + gates =================
__global__ __launch_bounds__(192) void node_fused_k(const float* __restrict__ agg,
                                                    const float* __restrict__ a_in,
                                                    const float* __restrict__ wtn,
                                                    const float* __restrict__ wtun,
                                                    const float* __restrict__ bn_in,
                                                    const float* __restrict__ bn_rec,
                                                    const int* __restrict__ agi,
                                                    float* __restrict__ a_out,
                                                    float* __restrict__ asum)
{
    __shared__ float xs[16][48];
    __shared__ float hs[16][32];
    __shared__ float S[16][192];
    __shared__ int garr[16];
    int t = threadIdx.x;
    int n0 = blockIdx.x * 16;

    reinterpret_cast<float4*>(&xs[0][0])[t] =
        reinterpret_cast<const float4*>(agg + (size_t)n0 * 48)[t];       // 192 float4
    if (t < 128) reinterpret_cast<float4*>(&hs[0][0])[t] =
        reinterpret_cast<const float4*>(a_in + (size_t)n0 * 32)[t];
    if (t >= 128 && t < 144) garr[t - 128] = agi[n0 + (t - 128)];
    __syncthreads();

    if (t < 96) {
        float w[48];
        const float4* wp4 = reinterpret_cast<const float4*>(wtn + t * 48);
        #pragma unroll
        for (int q = 0; q < 12; ++q) {
            float4 v = wp4[q];
            w[4*q] = v.x; w[4*q+1] = v.y; w[4*q+2] = v.z; w[4*q+3] = v.w;
        }
        float b = bn_in[t];
        #pragma unroll 4
        for (int i = 0; i < 16; ++i) {
            float sres = b;
            #pragma unroll
            for (int k = 0; k < 48; ++k) sres += xs[i][k] * w[k];
            S[i][t] = sres;
        }
    } else {
        float w[32];
        const float4* wp4 = reinterpret_cast<const float4*>(wtun + (t - 96) * 32);
        #pragma unroll
        for (int q = 0; q < 8; ++q) {
            float4 v = wp4[q];
            w[4*q] = v.x; w[4*q+1] = v.y; w[4*q+2] = v.z; w[4*q+3] = v.w;
        }
        float b = bn_rec[t - 96];
        #pragma unroll 4
        for (int i = 0; i < 16; ++i) {
            float sres = b;
            #pragma unroll
            for (int k = 0; k < 32; ++k) sres += hs[i][k] * w[k];
            S[i][t] = sres;
        }
    }
    __syncthreads();

    for (int idx = t; idx < 512; idx += 192) {
        int le = idx >> 5, cc = idx & 31;
        int n = n0 + le;
        float z  = 1.f / (1.f + expf(-(S[le][cc] + S[le][96 + cc])));
        float r  = 1.f / (1.f + expf(-(S[le][32 + cc] + S[le][128 + cc])));
        float hc = tanhf(S[le][64 + cc] + r * S[le][160 + cc]);
        float h  = hs[le][cc];
        float val = z * h + (1.f - z) * hc;
        a_out[(size_t)n * 32 + cc] = val;
        hs[le][cc] = val;                       // stash for block-level asum reduction
    }
    __syncthreads();

    if (t < 32) {
        int cc = t;
        int gprev = garr[0];
        float run = 0.f;
        #pragma unroll 4
        for (int le = 0; le < 16; ++le) {
            int gcur = garr[le];                // wave-uniform
            if (gcur != gprev) {
                atomicAdd(&asum[gprev * 32 + cc], run);
                run = 0.f; gprev = gcur;
            }
            run += hs[le][cc];
        }
        atomicAdd(&asum[gprev * 32 + cc], run);
    }
}

// ================= state GRU =================
__global__ void state_gru_k(const float* __restrict__ asum, const float* __restrict__ esum,
                            const float* __restrict__ s_in,
                            const float* __restrict__ Ws, const float* __restrict__ Us,
                            const float* __restrict__ bs_in, const float* __restrict__ bs_rec,
                            float* __restrict__ s_out)
{
    __shared__ float xs[80];
    __shared__ float hsv[16];
    __shared__ float S[48];
    __shared__ float Uh[16];
    int g = blockIdx.x;
    int t = threadIdx.x;
    if (t < 80) {
        float v;
        if (t < 32)      v = asum[g * 32 + t];
        else if (t < 64) v = esum[g * 32 + (t - 32)];
        else             v = s_in[g * 16 + (t - 64)];
        xs[t] = v;
        if (t >= 64) hsv[t - 64] = v;
    }
    __syncthreads();
    if (t < 48) {
        float gacc = bs_in[t];
        #pragma unroll
        for (int k = 0; k < 80; ++k) gacc += xs[k] * Ws[k * 48 + t];
        float u = bs_rec[t];
        #pragma unroll
        for (int k = 0; k < 16; ++k) u += hsv[k] * Us[k * 48 + t];
        if (t < 32) { S[t] = gacc + u; }
        else        { S[t] = gacc; Uh[t - 32] = u; }
    }
    __syncthreads();
    if (t < 16) {
        float z  = 1.f / (1.f + expf(-S[t]));
        float r  = 1.f / (1.f + expf(-S[16 + t]));
        float hc = tanhf(S[32 + t] + r * Uh[t]);
        s_out[g * 16 + t] = z * hsv[t] + (1.f - z) * hc;
    }
}

extern "C" void kernel_launch(void* const* d_in, const int* in_sizes, int n_in,
                              void* d_out, int out_size, void* d_ws, size_t ws_size,
                              hipStream_t stream)
{
    const float* a0      = (const float*)d_in[0];
    const float* e0      = (const float*)d_in[1];
    const float* s0      = (const float*)d_in[2];
    const int*   pair    = (const int*)d_in[3];
    const int*   agi     = (const int*)d_in[4];
    const int*   bgi     = (const int*)d_in[5];
    const float* kernelw = (const float*)d_in[6];
    const float* bias    = (const float*)d_in[7];
    const float* We      = (const float*)d_in[8];
    const float* Ue      = (const float*)d_in[9];
    const float* be_in   = (const float*)d_in[10];
    const float* be_rec  = (const float*)d_in[11];
    const float* Wn      = (const float*)d_in[12];
    const float* Un      = (const float*)d_in[13];
    const float* bn_in   = (const float*)d_in[14];
    const float* bn_rec  = (const float*)d_in[15];
    const float* Ws      = (const float*)d_in[16];
    const float* Us      = (const float*)d_in[17];
    const float* bs_in   = (const float*)d_in[18];
    const float* bs_rec  = (const float*)d_in[19];

    float* out_a = (float*)d_out;                    // N*32
    float* out_e = out_a + N_ATOMS * 32;             // E*32
    float* out_s = out_e + (size_t)N_EDGES * 32;     // G*16

    char* wp = (char*)d_ws;
    auto alloc = [&](size_t nf) { float* p = (float*)wp; wp += nf * sizeof(float); return p; };
    float* aW   = alloc((size_t)N_ATOMS * 32);
    float* eW   = alloc((size_t)N_EDGES * 32);
    float* sW   = alloc((size_t)N_GRAPH * 16);
    ushort_t* Yb = (ushort_t*)alloc((size_t)N_ATOMS * 1536 / 2);  // bf16, 30.7 MB
    float* Bn   = alloc((size_t)N_ATOMS * 48);
    float* agg  = alloc((size_t)N_ATOMS * 48);       // agg..esum contiguous memset
    float* asum = alloc((size_t)N_GRAPH * 32);
    float* esum = alloc((size_t)N_GRAPH * 32);
    float* PA   = alloc((size_t)N_ATOMS * 192);
    float* PS   = alloc((size_t)N_GRAPH * 96);
    float* wta  = alloc(6144);
    float* wts  = alloc(1536);
    float* wtee = alloc(6144);
    float* wtn  = alloc(4608);
    float* wtun = alloc(3072);
    ushort_t* kb = (ushort_t*)alloc(36864);          // 73728 bf16 = kernel(32x2304)
    size_t zero_bytes = ((size_t)N_ATOMS * 48 + 2 * N_GRAPH * 32) * sizeof(float);

    trans_k<<<372, 256, 0, stream>>>(We, Ue, Wn, Un, kernelw,
                                     wta, wts, wtee, wtn, wtun, kb);

    const float* a_in = a0;
    const float* e_in = e0;
    const float* s_in = s0;

    for (int step = 0; step < 2; ++step) {
        float* a_o = (step == 0) ? aW : out_a;
        float* e_o = (step == 0) ? eW : out_e;
        float* s_o = (step == 0) ? sW : out_s;

        hipMemsetAsync(agg, 0, zero_bytes, stream);
        pa_ps_k<<<N_ATOMS / 16 + N_GRAPH / 16, 192, 0, stream>>>(a_in, wta, PA,
                                                                 s_in, wts, be_in, PS);
        mid_k<<<NEB + (N_ATOMS + 31) / 32, 256, 0, stream>>>(e_in, wtee, be_rec, PA, PS,
                                                             pair, bgi, e_o, esum,
                                                             kb, bias, a_in, s_in, agi, Yb, Bn);
        edge_msg_k<<<N_EDGES / 4, 256, 0, stream>>>(e_o, pair, Yb, Bn, agg);
        node_fused_k<<<N_ATOMS / 16, 192, 0, stream>>>(agg, a_in, wtn, wtun,
                                                       bn_in, bn_rec, agi, a_o, asum);
        state_gru_k<<<N_GRAPH, 128, 0, stream>>>(asum, esum, s_in, Ws, Us, bs_in, bs_rec, s_o);

        a_in = a_o; e_in = e_o; s_in = s_o;
    }
}